// Round 4
// baseline (2019.885 us; speedup 1.0000x reference)
//
#include <hip/hip_runtime.h>

typedef unsigned short u16;
typedef __attribute__((ext_vector_type(8))) short short8;
typedef __attribute__((ext_vector_type(4))) float f32x4;

__device__ __forceinline__ u16 f2b(float f){
    unsigned u = __builtin_bit_cast(unsigned, f);
    u += 0x7fffu + ((u >> 16) & 1u);   // RNE
    return (u16)(u >> 16);
}
__device__ __forceinline__ float b2f(u16 s){
    unsigned u = ((unsigned)s) << 16;
    return __builtin_bit_cast(float, u);
}
__device__ __forceinline__ float sigm(float x){ return 1.f/(1.f + __expf(-x)); }

// LSTM cell: 5 exp2 + 3 rcp (sigm(i)*tanh(g) and sigm(o)*tanh(c) share one rcp each)
__device__ __forceinline__ float lstm_cell(const f32x4 g, float& cst){
    const float L2E = 1.4426950408889634f;
    float ei = __builtin_amdgcn_exp2f(-L2E * g[0]);
    float ef = __builtin_amdgcn_exp2f(-L2E * g[1]);
    float eg = __builtin_amdgcn_exp2f(-2.f * L2E * g[2]);
    float eo = __builtin_amdgcn_exp2f(-L2E * g[3]);
    float f_s = __builtin_amdgcn_rcpf(1.f + ef);
    float ig  = (1.f - eg) * __builtin_amdgcn_rcpf((1.f + ei) * (1.f + eg));
    float c = fmaf(f_s, cst, ig);
    cst = c;
    float ec = __builtin_amdgcn_exp2f(-2.f * L2E * c);
    return (1.f - ec) * __builtin_amdgcn_rcpf((1.f + eo) * (1.f + ec));
}

// ---------------- fp32 -> bf16 conversion ----------------
__global__ __launch_bounds__(256) void cvt_bf16(const float* __restrict__ s,
                                                u16* __restrict__ d, int n4){
    int i = blockIdx.x*256 + threadIdx.x;
    if (i < n4){
        float4 v = ((const float4*)s)[i];
        ushort4 o;
        o.x = f2b(v.x); o.y = f2b(v.y); o.z = f2b(v.z); o.w = f2b(v.w);
        ((ushort4*)d)[i] = o;
    }
}

// ---- W_ih cvt with row permutation: out row (unit*4+gate) = in row (gate*128+unit) ----
__global__ __launch_bounds__(192) void cvt_wih_perm(const float* __restrict__ s,
                                                    u16* __restrict__ d){
    int r = blockIdx.x;               // 0..511 input row
    int j = threadIdx.x;              // 0..191 float4 within row
    int g = r >> 7, u = r & 127;
    int ro = u * 4 + g;
    float4 v = ((const float4*)(s + (size_t)r * 768))[j];
    ushort4 o;
    o.x = f2b(v.x); o.y = f2b(v.y); o.z = f2b(v.z); o.w = f2b(v.w);
    ((ushort4*)(d + (size_t)ro * 768))[j] = o;
}

// ---- W_hh cvt + same row permutation (512 x 128) ----
__global__ __launch_bounds__(64) void cvt_whh_perm(const float* __restrict__ s,
                                                   u16* __restrict__ d){
    int r = blockIdx.x;               // 0..511 input row (g*128+u)
    int j = threadIdx.x;              // 0..31 float4
    if (j < 32){
        int g = r >> 7, u = r & 127;
        int ro = u * 4 + g;
        float4 v = ((const float4*)(s + (size_t)r * 128))[j];
        ushort4 o;
        o.x = f2b(v.x); o.y = f2b(v.y); o.z = f2b(v.z); o.w = f2b(v.w);
        ((ushort4*)(d + (size_t)ro * 128))[j] = o;
    }
}

// ---------------- embedding-gather + input projection GEMM ----------------
// pre[m, n] = sum_k E[tok[m], k] * Wt[n, k] + bias(n);  M x 1024, K=768
// Wt rows (and hence pre cols) are PERMUTED: within each 512-half, p = unit*4+gate.
__global__ __launch_bounds__(256) void gemm_embed(
    const u16* __restrict__ E, const int* __restrict__ tok,
    const u16* __restrict__ Wt, const float* __restrict__ bf_,
    const float* __restrict__ bb_, u16* __restrict__ pre)
{
    __shared__ __align__(16) u16 Asm[128*32];
    __shared__ __align__(16) u16 Bsm[128*32];
    const int m0 = blockIdx.x * 128, n0 = blockIdx.y * 128;
    const int tid = threadIdx.x;
    const int ar = tid >> 2, ch = (tid & 3) * 8;
    const u16* ap0 = E + (size_t)tok[m0 + ar] * 768 + ch;
    const u16* ap1 = E + (size_t)tok[m0 + 64 + ar] * 768 + ch;
    const u16* bp0 = Wt + (size_t)(n0 + ar) * 768 + ch;
    const u16* bp1 = Wt + (size_t)(n0 + 64 + ar) * 768 + ch;
    const int lane = tid & 63, wave = tid >> 6;
    const int wm = (wave >> 1) * 64, wn = (wave & 1) * 64;
    const int qr = lane >> 4, lr = lane & 15;
    f32x4 acc[4][4] = {};
    for (int k0 = 0; k0 < 768; k0 += 32){
        __syncthreads();
        *(short8*)&Asm[ar*32 + ch]      = *(const short8*)(ap0 + k0);
        *(short8*)&Asm[(64+ar)*32 + ch] = *(const short8*)(ap1 + k0);
        *(short8*)&Bsm[ar*32 + ch]      = *(const short8*)(bp0 + k0);
        *(short8*)&Bsm[(64+ar)*32 + ch] = *(const short8*)(bp1 + k0);
        __syncthreads();
        short8 af[4], bfr[4];
        #pragma unroll
        for (int i = 0; i < 4; ++i){
            af[i]  = *(const short8*)&Asm[(wm + i*16 + lr)*32 + qr*8];
            bfr[i] = *(const short8*)&Bsm[(wn + i*16 + lr)*32 + qr*8];
        }
        #pragma unroll
        for (int i = 0; i < 4; ++i)
            #pragma unroll
            for (int j = 0; j < 4; ++j)
                acc[i][j] = __builtin_amdgcn_mfma_f32_16x16x32_bf16(af[i], bfr[j], acc[i][j], 0, 0, 0);
    }
    #pragma unroll
    for (int j = 0; j < 4; ++j){
        int col = n0 + wn + j*16 + lr;
        int d = col >> 9, p = col & 511;
        int uu = p >> 2, gg = p & 3;
        float bias = (d ? bb_ : bf_)[gg*128 + uu];
        #pragma unroll
        for (int i = 0; i < 4; ++i){
            #pragma unroll
            for (int r = 0; r < 4; ++r){
                int row = m0 + wm + i*16 + qr*4 + r;
                pre[(size_t)row*1024 + col] = f2b(acc[i][j][r] + bias);
            }
        }
    }
}

// ---------------- MFMA LSTM scan (conservative bisect version) ----------------
// 8 chains per WG.  WG 0..3: word fwd; 4..7: word bwd; 8..71: sent fwd; 72..135: sent bwd.
// G[512 gates, 16 cols] = W_hh (A-frags, registers) x H (B-frags, LDS); cols 0..7 = chains.
// C-layout row = quad*4+reg -> p = gate row = wv*64 + t*16 + q*4 + r -> unit wv*16+t*4+q, gate r.
// Lanes c<8 run all 4 cells (tiles 0..3).  No swizzle, no asm barrier, no dynamic reg indexing.
__global__ __launch_bounds__(512, 2) void lstm_scan(
    const u16* __restrict__ preW, const u16* __restrict__ preS,
    const u16* __restrict__ WpWf, const u16* __restrict__ WpWb,
    const u16* __restrict__ WpSf, const u16* __restrict__ WpSb,
    float* __restrict__ fo, float* __restrict__ fs,
    u16* __restrict__ foB, u16* __restrict__ fsB)
{
    const int wg = blockIdx.x;
    const int tid = threadIdx.x;
    const int wv = tid >> 6, l = tid & 63;
    const int c = l & 15, q = l >> 4;

    const u16* pre; const u16* Wp; float* out; u16* outB;
    int T, dir, chain0;
    if (wg < 8){
        dir = (wg >= 4); T = 1024; chain0 = (wg & 3) * 8;
        pre = preW; Wp = dir ? WpWb : WpWf; out = fo; outB = foB;
    } else if (wg < 72){
        dir = 0; T = 64; chain0 = (wg - 8) * 8;
        pre = preS; Wp = WpSf; out = fs; outB = fsB;
    } else {
        dir = 1; T = 64; chain0 = (wg - 72) * 8;
        pre = preS; Wp = WpSb; out = fs; outB = fsB;
    }
    const int myChain = chain0 + (c & 7);
    const long rowbase = (long)myChain * T;

    // A-fragments of W_hh: row (wv*64 + t*16 + c), k = kb*32 + q*8 + j
    short8 Wf[4][4];
    {
        const u16* wbase = Wp + (size_t)(wv*64 + c) * 128 + q*8;
        #pragma unroll
        for (int t = 0; t < 4; ++t)
            #pragma unroll
            for (int kb = 0; kb < 4; ++kb)
                Wf[t][kb] = *(const short8*)(wbase + (size_t)t*16*128 + kb*32);
    }

    __shared__ __align__(16) u16  hL0[16*136];
    __shared__ __align__(16) u16  hL1[16*136];
    __shared__ __align__(16) float hist[8*1056];   // 8-step f32 history, chain stride 132
    for (int i = tid; i < 16*136; i += 512){ hL0[i] = 0; hL1[i] = 0; }
    __syncthreads();

    ushort4 pbA[4], pbB[4];
    {
        long row = rowbase + (dir ? (T-1) : 0);
        const u16* p0 = pre + row*1024 + dir*512 + wv*64 + q*4;
        #pragma unroll
        for (int t = 0; t < 4; ++t) pbA[t] = *(const ushort4*)(p0 + t*16);
    }
    float cs[4] = {0.f, 0.f, 0.f, 0.f};

#define STEP(IT, HCUR, HNXT, PCUR, PNXT)                                        \
    {                                                                           \
        const int it_ = (IT);                                                   \
        if (it_ + 1 < T){                                                       \
            long row = rowbase + (dir ? (long)(T-2-it_) : (long)(it_+1));       \
            const u16* pp = pre + row*1024 + dir*512 + wv*64 + q*4;             \
            _Pragma("unroll")                                                   \
            for (int t = 0; t < 4; ++t) PNXT[t] = *(const ushort4*)(pp + t*16); \
        }                                                                       \
        short8 Bf[4];                                                           \
        const u16* hb = &HCUR[(size_t)c*136 + q*8];                             \
        _Pragma("unroll")                                                       \
        for (int kb = 0; kb < 4; ++kb) Bf[kb] = *(const short8*)(hb + kb*32);   \
        f32x4 acc[4];                                                           \
        _Pragma("unroll")                                                       \
        for (int t = 0; t < 4; ++t){                                            \
            acc[t][0] = b2f(PCUR[t].x); acc[t][1] = b2f(PCUR[t].y);             \
            acc[t][2] = b2f(PCUR[t].z); acc[t][3] = b2f(PCUR[t].w);             \
        }                                                                       \
        _Pragma("unroll")                                                       \
        for (int kb = 0; kb < 4; ++kb)                                          \
            _Pragma("unroll")                                                   \
            for (int t = 0; t < 4; ++t)                                         \
                acc[t] = __builtin_amdgcn_mfma_f32_16x16x32_bf16(Wf[t][kb], Bf[kb], acc[t], 0, 0, 0); \
        if (c < 8){                                                             \
            float h0 = lstm_cell(acc[0], cs[0]);                                \
            float h1 = lstm_cell(acc[1], cs[1]);                                \
            float h2 = lstm_cell(acc[2], cs[2]);                                \
            float h3 = lstm_cell(acc[3], cs[3]);                                \
            const int ub = wv*16 + q;                                           \
            u16* hw = &HNXT[(size_t)c*136];                                     \
            hw[ub] = f2b(h0); hw[ub+4] = f2b(h1);                               \
            hw[ub+8] = f2b(h2); hw[ub+12] = f2b(h3);                            \
            float* hrow = &hist[(it_ & 7)*1056 + c*132];                        \
            hrow[ub] = h0; hrow[ub+4] = h1; hrow[ub+8] = h2; hrow[ub+12] = h3;  \
        }                                                                       \
        __syncthreads();                                                        \
    }

    for (int it8 = 0; it8 < T; it8 += 8){
        STEP(it8+0, hL0, hL1, pbA, pbB);
        STEP(it8+1, hL1, hL0, pbB, pbA);
        STEP(it8+2, hL0, hL1, pbA, pbB);
        STEP(it8+3, hL1, hL0, pbB, pbA);
        STEP(it8+4, hL0, hL1, pbA, pbB);
        STEP(it8+5, hL1, hL0, pbB, pbA);
        STEP(it8+6, hL0, hL1, pbA, pbB);
        STEP(it8+7, hL1, hL0, pbB, pbA);
        // coalesced flush of 8 steps x 8 chains x 128 units
        {
            int p_ = tid >> 3;            // 0..63 = (step, chain)
            int sId = p_ >> 3, cId = p_ & 7;
            int uF = (tid & 7) * 16;
            int itF = it8 + sId;
            long row = (long)(chain0 + cId) * T + (dir ? (long)(T-1-itF) : (long)itF);
            size_t o = (size_t)row * 256 + dir*128 + uF;
            const float* hsrc = &hist[sId*1056 + cId*132 + uF];
            float4 v0 = *(const float4*)(hsrc);
            float4 v1 = *(const float4*)(hsrc + 4);
            float4 v2 = *(const float4*)(hsrc + 8);
            float4 v3 = *(const float4*)(hsrc + 12);
            *(float4*)(out + o)      = v0;
            *(float4*)(out + o + 4)  = v1;
            *(float4*)(out + o + 8)  = v2;
            *(float4*)(out + o + 12) = v3;
            ushort4 w0{f2b(v0.x),f2b(v0.y),f2b(v0.z),f2b(v0.w)};
            ushort4 w1{f2b(v1.x),f2b(v1.y),f2b(v1.z),f2b(v1.w)};
            ushort4 w2{f2b(v2.x),f2b(v2.y),f2b(v2.z),f2b(v2.w)};
            ushort4 w3{f2b(v3.x),f2b(v3.y),f2b(v3.z),f2b(v3.w)};
            *(ushort4*)(outB + o)      = w0;
            *(ushort4*)(outB + o + 4)  = w1;
            *(ushort4*)(outB + o + 8)  = w2;
            *(ushort4*)(outB + o + 12) = w3;
        }
        __syncthreads();
    }
#undef STEP
}

// ---------------- gate GEMM + blend epilogue ----------------
__global__ __launch_bounds__(256) void gemm_gate(
    const u16* __restrict__ foB, const u16* __restrict__ fsB,
    const u16* __restrict__ gW, const float* __restrict__ gb,
    const float* __restrict__ fo, const float* __restrict__ fs,
    float* __restrict__ out)
{
    __shared__ __align__(16) u16 Asm[128*32];
    __shared__ __align__(16) u16 Bsm[128*32];
    const int m0 = blockIdx.x * 128, n0 = blockIdx.y * 128;
    const int tid = threadIdx.x;
    const int ar = tid >> 2, ch = (tid & 3) * 8;
    const u16* af0 = foB + (size_t)(m0 + ar) * 256 + ch;
    const u16* af1 = foB + (size_t)(m0 + 64 + ar) * 256 + ch;
    const u16* as0 = fsB + (size_t)(m0 + ar) * 256 + ch;
    const u16* as1 = fsB + (size_t)(m0 + 64 + ar) * 256 + ch;
    const u16* bp0 = gW + (size_t)(n0 + ar) * 512 + ch;
    const u16* bp1 = gW + (size_t)(n0 + 64 + ar) * 512 + ch;
    const int lane = tid & 63, wave = tid >> 6;
    const int wm = (wave >> 1) * 64, wn = (wave & 1) * 64;
    const int qr = lane >> 4, lr = lane & 15;
    f32x4 acc[4][4] = {};
    for (int k0 = 0; k0 < 512; k0 += 32){
        __syncthreads();
        const u16* s0 = (k0 < 256) ? (af0 + k0) : (as0 + (k0 - 256));
        const u16* s1 = (k0 < 256) ? (af1 + k0) : (as1 + (k0 - 256));
        *(short8*)&Asm[ar*32 + ch]      = *(const short8*)s0;
        *(short8*)&Asm[(64+ar)*32 + ch] = *(const short8*)s1;
        *(short8*)&Bsm[ar*32 + ch]      = *(const short8*)(bp0 + k0);
        *(short8*)&Bsm[(64+ar)*32 + ch] = *(const short8*)(bp1 + k0);
        __syncthreads();
        short8 af[4], bfr[4];
        #pragma unroll
        for (int i = 0; i < 4; ++i){
            af[i]  = *(const short8*)&Asm[(wm + i*16 + lr)*32 + qr*8];
            bfr[i] = *(const short8*)&Bsm[(wn + i*16 + lr)*32 + qr*8];
        }
        #pragma unroll
        for (int i = 0; i < 4; ++i)
            #pragma unroll
            for (int j = 0; j < 4; ++j)
                acc[i][j] = __builtin_amdgcn_mfma_f32_16x16x32_bf16(af[i], bfr[j], acc[i][j], 0, 0, 0);
    }
    #pragma unroll
    for (int j = 0; j < 4; ++j){
        int col = n0 + wn + j*16 + lr;
        float bias = gb[col];
        #pragma unroll
        for (int i = 0; i < 4; ++i){
            #pragma unroll
            for (int r = 0; r < 4; ++r){
                int row = m0 + wm + i*16 + qr*4 + r;
                size_t o = (size_t)row*256 + col;
                float gamma = sigm(acc[i][j][r] + bias);
                out[o] = gamma * fo[o] + (1.f - gamma) * fs[o];
            }
        }
    }
}

extern "C" void kernel_launch(void* const* d_in, const int* in_sizes, int n_in,
                              void* d_out, int out_size, void* d_ws, size_t ws_size,
                              hipStream_t stream)
{
    (void)in_sizes; (void)n_in; (void)out_size; (void)ws_size;
    const int*   wordTok = (const int*)d_in[0];
    const int*   sentTok = (const int*)d_in[1];
    const float* E       = (const float*)d_in[3];
    const float* WihWf   = (const float*)d_in[4];
    const float* WhhWf   = (const float*)d_in[5];
    const float* bWf     = (const float*)d_in[6];
    const float* WihWb   = (const float*)d_in[7];
    const float* WhhWb   = (const float*)d_in[8];
    const float* bWb     = (const float*)d_in[9];
    const float* WihSf   = (const float*)d_in[10];
    const float* WhhSf   = (const float*)d_in[11];
    const float* bSf     = (const float*)d_in[12];
    const float* WihSb   = (const float*)d_in[13];
    const float* WhhSb   = (const float*)d_in[14];
    const float* bSb     = (const float*)d_in[15];
    const float* gateW   = (const float*)d_in[16];
    const float* gateB   = (const float*)d_in[17];
    float* out = (float*)d_out;

    char* w = (char*)d_ws;
    u16* Eb   = (u16*)w;  w += (size_t)30522*768*2;
    u16* Ww   = (u16*)w;  w += (size_t)1024*768*2;
    u16* Ws_  = (u16*)w;  w += (size_t)1024*768*2;
    u16* gWb  = (u16*)w;  w += (size_t)256*512*2;
    u16* WpWf = (u16*)w;  w += (size_t)512*128*2;
    u16* WpWb = (u16*)w;  w += (size_t)512*128*2;
    u16* WpSf = (u16*)w;  w += (size_t)512*128*2;
    u16* WpSb = (u16*)w;  w += (size_t)512*128*2;
    u16* preW = (u16*)w;  w += (size_t)32768*1024*2;
    u16* preS = (u16*)w;  w += (size_t)32768*1024*2;
    float* fo = (float*)w; w += (size_t)32768*256*4;
    float* fs = (float*)w; w += (size_t)32768*256*4;
    u16* foB  = (u16*)w;  w += (size_t)32768*256*2;
    u16* fsB  = (u16*)w;  w += (size_t)32768*256*2;

    const int nE4 = 30522*768/4;
    cvt_bf16<<<(nE4+255)/256, 256, 0, stream>>>(E, Eb, nE4);
    cvt_wih_perm<<<512, 192, 0, stream>>>(WihWf, Ww);
    cvt_wih_perm<<<512, 192, 0, stream>>>(WihWb, Ww + 512*768);
    cvt_wih_perm<<<512, 192, 0, stream>>>(WihSf, Ws_);
    cvt_wih_perm<<<512, 192, 0, stream>>>(WihSb, Ws_ + 512*768);
    cvt_whh_perm<<<512, 64, 0, stream>>>(WhhWf, WpWf);
    cvt_whh_perm<<<512, 64, 0, stream>>>(WhhWb, WpWb);
    cvt_whh_perm<<<512, 64, 0, stream>>>(WhhSf, WpSf);
    cvt_whh_perm<<<512, 64, 0, stream>>>(WhhSb, WpSb);
    const int nG4 = 256*512/4;
    cvt_bf16<<<(nG4+255)/256, 256, 0, stream>>>(gateW, gWb, nG4);

    gemm_embed<<<dim3(256,8), 256, 0, stream>>>(Eb, wordTok, Ww, bWf, bWb, preW);
    gemm_embed<<<dim3(256,8), 256, 0, stream>>>(Eb, sentTok, Ws_, bSf, bSb, preS);
    lstm_scan<<<136, 512, 0, stream>>>(preW, preS, WpWf, WpWb, WpSf, WpSb,
                                       fo, fs, foB, fsB);
    gemm_gate<<<dim3(256,2), 256, 0, stream>>>(foB, fsB, gWb, gateB, fo, fs, out);
}